// Round 5
// baseline (19.470 us; speedup 1.0000x reference)
//
#include <hip/hip_runtime.h>

#define BQ  8     // batch of queries
#define DIM 128   // embedding dim

typedef __attribute__((ext_vector_type(8))) short bf16x8;  // 8 bf16 = 4 VGPR
typedef __attribute__((ext_vector_type(4))) float f32x4;   // MFMA C/D

// pack two f32 into one u32 of 2 bf16 (round-half-up), elem0=x(lo), elem1=y(hi)
__device__ __forceinline__ unsigned pack2(float x, float y) {
    unsigned xb = __float_as_uint(x) + 0x8000u;
    unsigned yb = __float_as_uint(y) + 0x8000u;
    return __builtin_amdgcn_perm(yb, xb, 0x07060302u);
}

// score[b][e] = sqrt(||t_e||^2 - 2 t_e.p_b + ||p_b||^2) + bh[b] + bt[e]
// -2 t.p via mfma_f32_16x16x32_bf16: A = 16-entity tile (M=16,K=128),
// B = -2*pred (K=128, N=16; cols 8..15 dead). C/D: col=lane&15 (query),
// row=(lane>>4)*4+reg (entity)  [m89-verified]. K-slot mapping is
// self-consistent between A and B (dot is permutation-invariant in k).
__global__ __launch_bounds__(256) void transe_mfma(
    const int*   __restrict__ head,
    const int*   __restrict__ relation,
    const int*   __restrict__ tail,
    const float* __restrict__ emb_entity,
    const float* __restrict__ emb_relation,
    const float* __restrict__ bias_head,
    const float* __restrict__ bias_tail,
    float*       __restrict__ out,
    int E)
{
    __shared__ float pred[BQ][DIM];
    __shared__ float p2_s[BQ];
    __shared__ float bh_s[BQ];

    const int t = threadIdx.x;

    for (int i = t; i < BQ * DIM; i += 256) {
        int b = i >> 7, d = i & 127;
        pred[b][d] = emb_entity[(size_t)head[b] * DIM + d]
                   + emb_relation[(size_t)relation[b] * DIM + d];
    }
    if (t < BQ) bh_s[t] = bias_head[head[t]];
    __syncthreads();
    {   // p2_s[q] = ||pred[q]||^2 : 32 threads per query
        int q = t >> 5, l5 = t & 31;
        float4 v = *(const float4*)&pred[q][l5 << 2];
        float s = v.x*v.x + v.y*v.y + v.z*v.z + v.w*v.w;
        s += __shfl_xor(s, 1, 32);  s += __shfl_xor(s, 2, 32);
        s += __shfl_xor(s, 4, 32);  s += __shfl_xor(s, 8, 32);
        s += __shfl_xor(s, 16, 32);
        if (l5 == 0) p2_s[q] = s;
    }
    __syncthreads();

    const int lane = t & 63;
    const int wid  = t >> 6;       // wave within block (0..3)
    const int col  = lane & 15;    // query column (8..15 dead)
    const int g    = lane >> 4;    // k-group 0..3

    // B fragments: elem j of frag mi = -2*pred[col][mi*32 + g*8 + j]
    bf16x8 B0, B1, B2, B3;
    {
        union { unsigned u[4]; bf16x8 v; } bb;
        #pragma unroll
        for (int mi = 0; mi < 4; ++mi) {
            #pragma unroll
            for (int jp = 0; jp < 4; ++jp) {
                float x = 0.f, y = 0.f;
                if (col < BQ) {
                    const float* pp = &pred[col][mi*32 + g*8 + jp*2];
                    x = -2.f * pp[0];
                    y = -2.f * pp[1];
                }
                bb.u[jp] = pack2(x, y);
            }
            if      (mi == 0) B0 = bb.v;
            else if (mi == 1) B1 = bb.v;
            else if (mi == 2) B2 = bb.v;
            else              B3 = bb.v;
        }
    }
    const float p2c = (col < BQ) ? p2_s[col] : 0.f;
    const float bhc = (col < BQ) ? bh_s[col] : 0.f;

    const int ntiles  = (E + 15) >> 4;
    const int wstride = gridDim.x * 4;
    int tile = blockIdx.x * 4 + wid;
    if (tile >= ntiles) return;

    // lane loads row tail[tile*16+col], fp32 dims g*8+{0..7}+32*mi (32B x4)
#define STAGE(TL, TE, BT, F0,F1,F2,F3,F4,F5,F6,F7) do {                     \
        int _e = min((TL)*16 + col, E-1);                                   \
        TE = tail[_e];                                                      \
        BT = bias_tail[TE];                                                 \
        const float* _r = emb_entity + (size_t)TE * DIM + g*8;              \
        F0 = *(const float4*)(_r);        F1 = *(const float4*)(_r+4);      \
        F2 = *(const float4*)(_r+32);     F3 = *(const float4*)(_r+36);     \
        F4 = *(const float4*)(_r+64);     F5 = *(const float4*)(_r+68);     \
        F6 = *(const float4*)(_r+96);     F7 = *(const float4*)(_r+100);    \
    } while (0)

#define SSQ4(S, V) S = fmaf(V.x,V.x, fmaf(V.y,V.y, fmaf(V.z,V.z, fmaf(V.w,V.w, S))))

    int teA; float btA; float4 a0,a1,a2,a3,a4,a5,a6,a7;
    STAGE(tile, teA, btA, a0,a1,a2,a3,a4,a5,a6,a7);

    while (true) {
        int  tn   = tile + wstride;
        bool more = (tn < ntiles);
        int teB; float btB; float4 b0,b1,b2,b3,b4,b5,b6,b7;
        if (more) STAGE(tn, teB, btB, b0,b1,b2,b3,b4,b5,b6,b7);

        // ||t||^2 partial over this lane's 32 dims, reduce across k-groups
        float ss = 0.f;
        SSQ4(ss, a0); SSQ4(ss, a1); SSQ4(ss, a2); SSQ4(ss, a3);
        SSQ4(ss, a4); SSQ4(ss, a5); SSQ4(ss, a6); SSQ4(ss, a7);
        float t2 = ss + __shfl_xor(ss, 16, 64);
        t2 += __shfl_xor(t2, 32, 64);

        // fp32 -> bf16 A fragments (same k-slot mapping as B)
        union { unsigned u[4]; bf16x8 v; } A0, A1, A2, A3;
        A0.u[0]=pack2(a0.x,a0.y); A0.u[1]=pack2(a0.z,a0.w);
        A0.u[2]=pack2(a1.x,a1.y); A0.u[3]=pack2(a1.z,a1.w);
        A1.u[0]=pack2(a2.x,a2.y); A1.u[1]=pack2(a2.z,a2.w);
        A1.u[2]=pack2(a3.x,a3.y); A1.u[3]=pack2(a3.z,a3.w);
        A2.u[0]=pack2(a4.x,a4.y); A2.u[1]=pack2(a4.z,a4.w);
        A2.u[2]=pack2(a5.x,a5.y); A2.u[3]=pack2(a5.z,a5.w);
        A3.u[0]=pack2(a6.x,a6.y); A3.u[1]=pack2(a6.z,a6.w);
        A3.u[2]=pack2(a7.x,a7.y); A3.u[3]=pack2(a7.z,a7.w);

        f32x4 C = {0.f, 0.f, 0.f, 0.f};
        C = __builtin_amdgcn_mfma_f32_16x16x32_bf16(A0.v, B0, C, 0, 0, 0);
        C = __builtin_amdgcn_mfma_f32_16x16x32_bf16(A1.v, B1, C, 0, 0, 0);
        C = __builtin_amdgcn_mfma_f32_16x16x32_bf16(A2.v, B2, C, 0, 0, 0);
        C = __builtin_amdgcn_mfma_f32_16x16x32_bf16(A3.v, B3, C, 0, 0, 0);

        // epilogue: lane covers entities g*4+i (query=col)
        int rb = g * 4;
        float t20 = __shfl(t2, rb+0, 64), bt0 = __shfl(btA, rb+0, 64);
        float t21 = __shfl(t2, rb+1, 64), bt1 = __shfl(btA, rb+1, 64);
        float t22 = __shfl(t2, rb+2, 64), bt2 = __shfl(btA, rb+2, 64);
        float t23 = __shfl(t2, rb+3, 64), bt3 = __shfl(btA, rb+3, 64);
        float r0 = sqrtf(fmaxf(C[0] + t20 + p2c, 0.f)) + bhc + bt0;
        float r1 = sqrtf(fmaxf(C[1] + t21 + p2c, 0.f)) + bhc + bt1;
        float r2 = sqrtf(fmaxf(C[2] + t22 + p2c, 0.f)) + bhc + bt2;
        float r3 = sqrtf(fmaxf(C[3] + t23 + p2c, 0.f)) + bhc + bt3;

        if (col < BQ) {
            int e0 = tile * 16 + rb;
            if (e0 + 4 <= E) {
                float4 r; r.x = r0; r.y = r1; r.z = r2; r.w = r3;
                *(float4*)&out[(size_t)col * E + e0] = r;
            } else {
                if (e0 + 0 < E) out[(size_t)col*E + e0 + 0] = r0;
                if (e0 + 1 < E) out[(size_t)col*E + e0 + 1] = r1;
                if (e0 + 2 < E) out[(size_t)col*E + e0 + 2] = r2;
                if (e0 + 3 < E) out[(size_t)col*E + e0 + 3] = r3;
            }
        }

        if (!more) break;
        tile = tn; teA = teB; btA = btB;
        a0=b0; a1=b1; a2=b2; a3=b3; a4=b4; a5=b5; a6=b6; a7=b7;
    }
#undef STAGE
#undef SSQ4
}

extern "C" void kernel_launch(void* const* d_in, const int* in_sizes, int n_in,
                              void* d_out, int out_size, void* d_ws, size_t ws_size,
                              hipStream_t stream) {
    const int*   head         = (const int*)  d_in[0];
    const int*   relation     = (const int*)  d_in[1];
    const int*   tail         = (const int*)  d_in[2];
    const float* emb_entity   = (const float*)d_in[3];
    const float* emb_relation = (const float*)d_in[4];
    const float* bias_head    = (const float*)d_in[5];
    const float* bias_tail    = (const float*)d_in[6];
    float* out = (float*)d_out;

    const int E = in_sizes[2];           // 100000
    const int ntiles = (E + 15) >> 4;    // 6250

    // 1024 blocks x 4 waves = 4096 waves; ~1.5 tiles/wave, depth-1 prefetch
    int blocks = 1024;
    int maxb = (ntiles + 3) / 4;
    if (blocks > maxb) blocks = maxb;

    hipLaunchKernelGGL(transe_mfma, dim3(blocks), dim3(256), 0, stream,
                       head, relation, tail, emb_entity, emb_relation,
                       bias_head, bias_tail, out, E);
}

// Round 6
// 17.908 us; speedup vs baseline: 1.0872x; 1.0872x over previous
//
#include <hip/hip_runtime.h>

#define BQ  8     // batch of queries
#define DIM 128   // embedding dim

typedef __attribute__((ext_vector_type(8))) short bf16x8;  // 8 bf16 = 4 VGPR
typedef __attribute__((ext_vector_type(4))) float f32x4;   // MFMA C/D

// pack two f32 into one u32 of 2 bf16 (round-half-up), elem0=x(lo), elem1=y(hi)
__device__ __forceinline__ unsigned pack2(float x, float y) {
    unsigned xb = __float_as_uint(x) + 0x8000u;
    unsigned yb = __float_as_uint(y) + 0x8000u;
    return __builtin_amdgcn_perm(yb, xb, 0x07060302u);
}

// One wave = one 16-entity tile, no loop. score = sqrt(||t||^2 - 2 t.p +
// ||p||^2) + bh + bt ; -2 t.p via mfma_f32_16x16x32_bf16 (4 MFMAs, K=128).
// C/D: col=lane&15 (query), row=(lane>>4)*4+reg (entity) [m89-verified].
// All global loads (tail idx first, then rows+bias) issue before the first
// __syncthreads so latency overlaps the pred-build phase.
__global__ __launch_bounds__(256) void transe_mfma(
    const int*   __restrict__ head,
    const int*   __restrict__ relation,
    const int*   __restrict__ tail,
    const float* __restrict__ emb_entity,
    const float* __restrict__ emb_relation,
    const float* __restrict__ bias_head,
    const float* __restrict__ bias_tail,
    float*       __restrict__ out,
    int E)
{
    __shared__ float pred[BQ][DIM];
    __shared__ float p2_s[BQ];
    __shared__ float bh_s[BQ];

    const int t    = threadIdx.x;
    const int lane = t & 63;
    const int wid  = t >> 6;       // wave in block (0..3)
    const int col  = lane & 15;    // entity-row selector / query column
    const int g    = lane >> 4;    // k-group 0..3

    const int ntiles = (E + 15) >> 4;
    const int tile   = blockIdx.x * 4 + wid;
    const bool live  = (tile < ntiles);

    // ---- issue the dependent gather chain as early as possible ----
    int e0 = tile * 16;
    int te = 0;
    if (live) te = tail[min(e0 + col, E - 1)];

    // pred[b][d] = emb_entity[head[b]][d] + emb_relation[relation[b]][d]
    for (int i = t; i < BQ * DIM; i += 256) {
        int b = i >> 7, d = i & 127;
        pred[b][d] = emb_entity[(size_t)head[b] * DIM + d]
                   + emb_relation[(size_t)relation[b] * DIM + d];
    }
    if (t < BQ) bh_s[t] = bias_head[head[t]];

    // rows + bias for this tile: issue BEFORE the barrier so the barrier's
    // vmcnt(0) drain overlaps this latency with the pred-build latency.
    float bt = 0.f;
    float4 a0, a1, a2, a3, a4, a5, a6, a7;
    a0=a1=a2=a3=a4=a5=a6=a7 = make_float4(0.f,0.f,0.f,0.f);
    if (live) {
        bt = bias_tail[te];
        const float* r = emb_entity + (size_t)te * DIM + g * 8;
        a0 = *(const float4*)(r);       a1 = *(const float4*)(r + 4);
        a2 = *(const float4*)(r + 32);  a3 = *(const float4*)(r + 36);
        a4 = *(const float4*)(r + 64);  a5 = *(const float4*)(r + 68);
        a6 = *(const float4*)(r + 96);  a7 = *(const float4*)(r + 100);
    }
    __syncthreads();

    {   // p2_s[q] = ||pred[q]||^2 : 32 threads per query
        int q = t >> 5, l5 = t & 31;
        float4 v = *(const float4*)&pred[q][l5 << 2];
        float s = v.x*v.x + v.y*v.y + v.z*v.z + v.w*v.w;
        s += __shfl_xor(s, 1, 32);  s += __shfl_xor(s, 2, 32);
        s += __shfl_xor(s, 4, 32);  s += __shfl_xor(s, 8, 32);
        s += __shfl_xor(s, 16, 32);
        if (l5 == 0) p2_s[q] = s;
    }
    __syncthreads();

    if (!live) return;

    // B fragments: elem j of frag mi = -2*pred[col][mi*32 + g*8 + j]
    bf16x8 B0, B1, B2, B3;
    {
        union { unsigned u[4]; bf16x8 v; } bb;
        #pragma unroll
        for (int mi = 0; mi < 4; ++mi) {
            #pragma unroll
            for (int jp = 0; jp < 4; ++jp) {
                float x = 0.f, y = 0.f;
                if (col < BQ) {
                    const float* pp = &pred[col][mi*32 + g*8 + jp*2];
                    x = -2.f * pp[0];
                    y = -2.f * pp[1];
                }
                bb.u[jp] = pack2(x, y);
            }
            if      (mi == 0) B0 = bb.v;
            else if (mi == 1) B1 = bb.v;
            else if (mi == 2) B2 = bb.v;
            else              B3 = bb.v;
        }
    }
    const float p2c = (col < BQ) ? p2_s[col] : 0.f;
    const float bhc = (col < BQ) ? bh_s[col] : 0.f;

#define SSQ4(S, V) S = fmaf(V.x,V.x, fmaf(V.y,V.y, fmaf(V.z,V.z, fmaf(V.w,V.w, S))))
    // ||t||^2 partial over this lane's 32 dims, reduce across the 4 k-groups
    float ss = 0.f;
    SSQ4(ss, a0); SSQ4(ss, a1); SSQ4(ss, a2); SSQ4(ss, a3);
    SSQ4(ss, a4); SSQ4(ss, a5); SSQ4(ss, a6); SSQ4(ss, a7);
    float t2 = ss + __shfl_xor(ss, 16, 64);
    t2 += __shfl_xor(t2, 32, 64);
#undef SSQ4

    // fp32 -> bf16 A fragments (k-slot mapping identical to B's)
    union { unsigned u[4]; bf16x8 v; } A0, A1, A2, A3;
    A0.u[0]=pack2(a0.x,a0.y); A0.u[1]=pack2(a0.z,a0.w);
    A0.u[2]=pack2(a1.x,a1.y); A0.u[3]=pack2(a1.z,a1.w);
    A1.u[0]=pack2(a2.x,a2.y); A1.u[1]=pack2(a2.z,a2.w);
    A1.u[2]=pack2(a3.x,a3.y); A1.u[3]=pack2(a3.z,a3.w);
    A2.u[0]=pack2(a4.x,a4.y); A2.u[1]=pack2(a4.z,a4.w);
    A2.u[2]=pack2(a5.x,a5.y); A2.u[3]=pack2(a5.z,a5.w);
    A3.u[0]=pack2(a6.x,a6.y); A3.u[1]=pack2(a6.z,a6.w);
    A3.u[2]=pack2(a7.x,a7.y); A3.u[3]=pack2(a7.z,a7.w);

    f32x4 C = {0.f, 0.f, 0.f, 0.f};
    C = __builtin_amdgcn_mfma_f32_16x16x32_bf16(A0.v, B0, C, 0, 0, 0);
    C = __builtin_amdgcn_mfma_f32_16x16x32_bf16(A1.v, B1, C, 0, 0, 0);
    C = __builtin_amdgcn_mfma_f32_16x16x32_bf16(A2.v, B2, C, 0, 0, 0);
    C = __builtin_amdgcn_mfma_f32_16x16x32_bf16(A3.v, B3, C, 0, 0, 0);

    // epilogue: this lane covers entities g*4+{0..3} of the tile (query=col)
    int rb = g * 4;
    float t20 = __shfl(t2, rb+0, 64), bt0 = __shfl(bt, rb+0, 64);
    float t21 = __shfl(t2, rb+1, 64), bt1 = __shfl(bt, rb+1, 64);
    float t22 = __shfl(t2, rb+2, 64), bt2 = __shfl(bt, rb+2, 64);
    float t23 = __shfl(t2, rb+3, 64), bt3 = __shfl(bt, rb+3, 64);
    float r0 = sqrtf(fmaxf(C[0] + t20 + p2c, 0.f)) + bhc + bt0;
    float r1 = sqrtf(fmaxf(C[1] + t21 + p2c, 0.f)) + bhc + bt1;
    float r2 = sqrtf(fmaxf(C[2] + t22 + p2c, 0.f)) + bhc + bt2;
    float r3 = sqrtf(fmaxf(C[3] + t23 + p2c, 0.f)) + bhc + bt3;

    if (col < BQ) {
        int e = e0 + rb;
        if (e + 4 <= E) {
            float4 r; r.x = r0; r.y = r1; r.z = r2; r.w = r3;
            *(float4*)&out[(size_t)col * E + e] = r;
        } else {
            if (e + 0 < E) out[(size_t)col*E + e + 0] = r0;
            if (e + 1 < E) out[(size_t)col*E + e + 1] = r1;
            if (e + 2 < E) out[(size_t)col*E + e + 2] = r2;
            if (e + 3 < E) out[(size_t)col*E + e + 3] = r3;
        }
    }
}

extern "C" void kernel_launch(void* const* d_in, const int* in_sizes, int n_in,
                              void* d_out, int out_size, void* d_ws, size_t ws_size,
                              hipStream_t stream) {
    const int*   head         = (const int*)  d_in[0];
    const int*   relation     = (const int*)  d_in[1];
    const int*   tail         = (const int*)  d_in[2];
    const float* emb_entity   = (const float*)d_in[3];
    const float* emb_relation = (const float*)d_in[4];
    const float* bias_head    = (const float*)d_in[5];
    const float* bias_tail    = (const float*)d_in[6];
    float* out = (float*)d_out;

    const int E = in_sizes[2];           // 100000
    const int ntiles = (E + 15) >> 4;    // 6250 (E is a multiple of 16)
    const int blocks = (ntiles + 3) / 4; // one wave per tile, 4 waves/block

    hipLaunchKernelGGL(transe_mfma, dim3(blocks), dim3(256), 0, stream,
                       head, relation, tail, emb_entity, emb_relation,
                       bias_head, bias_tail, out, E);
}